// Round 10
// baseline (252.052 us; speedup 1.0000x reference)
//
#include <hip/hip_runtime.h>
#include <math.h>

#define NB 128
#define NS 256
#define NH 768
#define NL 24
#define ASTR 68    // A-tile LDS stride (words): 68%32=4 -> 2-way banks, 16B-aligned rows
#define SCLS 28    // scl row stride (words): 16B-aligned rows, col 24 = pad
#define E_BYTES (NB*NS*NL*4)   // 3,145,728 B

// Fused kernel. Blocks [0,NB): Viterbi consumers (dispatched first). Blocks
// [NB, NB+NB*8): emission producers, one 32-token tile each (R4 emis verbatim).
// Per-TILE flags let each consumer's forward chase the producers tile-by-tile,
// so total span ~= max(emis span, vit span) instead of their sum.
// LDS union 37.3 KB -> 4 blocks/CU (preserves R4 emis residency).
__global__ __launch_bounds__(256) void ner_fused(
    const float* __restrict__ tf, const int* __restrict__ tlm,
    const float* __restrict__ W, const float* __restrict__ bias,
    const float* __restrict__ trans, const float* __restrict__ st,
    const float* __restrict__ en, float* __restrict__ E,
    int* __restrict__ flags, int* __restrict__ out)
{
    __shared__ __align__(16) unsigned char smem[37376];
    const int tid = threadIdx.x;

    if (blockIdx.x >= NB) {
        // ================= emission producer (R4 body verbatim) =================
        const int bid  = blockIdx.x - NB;
        const int b    = bid >> 3;
        const int tile = (bid & 7) << 5;            // token base of this tile
        if (tlm[b*NS + tile] == 0) {                // prefix mask: whole tile invalid
            if (tid == 0)
                __hip_atomic_store(flags + bid, 1, __ATOMIC_RELEASE, __HIP_MEMORY_SCOPE_AGENT);
            return;
        }

        float* lds = (float*)smem;                  // 6400 floats = 25.6 KB
        float* As = lds;                            // [32][ASTR] = 2176 words
        float* Ws = lds + 32*ASTR;                  // [64][24]   = 1536 words
        float* Pr = lds;                            // [8][32][25] reduction (after K-loop)

        const int tok  = tid & 15;
        const int ksub = tid >> 4;                  // 0..15
        const int kk   = ksub << 2;                 // k base within 64-chunk
        const int rot  = ksub & 3;                  // bank-phase rotation

        float acc0[NL], acc1[NL];
        #pragma unroll
        for (int l = 0; l < NL; ++l) { acc0[l] = 0.f; acc1[l] = 0.f; }

        const float* tfb = tf + (size_t)(b*NS)*NH;

        // A-stage addressing (fixed per thread)
        const int rowA0 = tid >> 4,         c4A0 = tid & 15;
        const int rowA1 = (tid + 256) >> 4, c4A1 = tid & 15;
        int trow0 = tile + rowA0 + 1; if (trow0 > 255) trow0 = 255;
        int trow1 = tile + rowA1 + 1; if (trow1 > 255) trow1 = 255;
        const float* srcA0 = tfb + (size_t)trow0*NH + (c4A0 << 2);
        const float* srcA1 = tfb + (size_t)trow1*NH + (c4A1 << 2);

        float4 pa0, pa1, pw0, pw1;
        // ---- prologue: load + commit chunk 0 ----
        pa0 = *(const float4*)(srcA0);
        pa1 = *(const float4*)(srcA1);
        {
            const float4* wsrc = (const float4*)(W);
            pw0 = wsrc[tid];
            if (tid < 128) pw1 = wsrc[tid + 256];
        }
        {
            float* d0 = As + rowA0*ASTR + (c4A0 << 2);
            d0[0]=pa0.x; d0[1]=pa0.y; d0[2]=pa0.z; d0[3]=pa0.w;
            float* d1 = As + rowA1*ASTR + (c4A1 << 2);
            d1[0]=pa1.x; d1[1]=pa1.y; d1[2]=pa1.z; d1[3]=pa1.w;
            ((float4*)Ws)[tid] = pw0;
            if (tid < 128) ((float4*)Ws)[tid + 256] = pw1;
        }
        __syncthreads();

        for (int kc0 = 0; kc0 < NH; kc0 += 64) {
            const bool more = (kc0 + 64 < NH);
            if (more) {   // issue next chunk's loads now; wait lands after compute
                pa0 = *(const float4*)(srcA0 + kc0 + 64);
                pa1 = *(const float4*)(srcA1 + kc0 + 64);
                const float4* wsrc = (const float4*)(W + (size_t)(kc0 + 64)*NL);
                pw0 = wsrc[tid];
                if (tid < 128) pw1 = wsrc[tid + 256];
            }

            const float* A0 = As + tok*ASTR + kk;
            const float* A1 = A0 + 16*ASTR;
            const float* Wr = Ws + kk*NL;
            #pragma unroll
            for (int s = 0; s < 4; ++s) {
                const int j = (s + rot) & 3;        // rotated row order (bank phase)
                float a0 = A0[j];
                float a1 = A1[j];
                const float4* w4 = (const float4*)(Wr + j*NL);
                float wv[NL];
                #pragma unroll
                for (int i = 0; i < 6; ++i) {       // 6 broadcast ds_read_b128
                    float4 w = w4[i];
                    wv[4*i+0] = w.x; wv[4*i+1] = w.y; wv[4*i+2] = w.z; wv[4*i+3] = w.w;
                }
                #pragma unroll
                for (int l = 0; l < NL; ++l) {
                    acc0[l] = fmaf(a0, wv[l], acc0[l]);
                    acc1[l] = fmaf(a1, wv[l], acc1[l]);
                }
            }
            __syncthreads();                        // all reads of this chunk done

            if (more) {                             // commit prefetched chunk to LDS
                float* d0 = As + rowA0*ASTR + (c4A0 << 2);
                d0[0]=pa0.x; d0[1]=pa0.y; d0[2]=pa0.z; d0[3]=pa0.w;
                float* d1 = As + rowA1*ASTR + (c4A1 << 2);
                d1[0]=pa1.x; d1[1]=pa1.y; d1[2]=pa1.z; d1[3]=pa1.w;
                ((float4*)Ws)[tid] = pw0;
                if (tid < 128) ((float4*)Ws)[tid + 256] = pw1;
                __syncthreads();
            }
        }

        // ---- fold 16 ksub partials -> 8, then final (fixed order) ----
        if (ksub >= 8) {
            float* p = Pr + ((ksub-8)*32 + tok)*25;
            float* q = p + 16*25;
            #pragma unroll
            for (int l = 0; l < NL; ++l) { p[l] = acc0[l]; q[l] = acc1[l]; }
        }
        __syncthreads();
        if (ksub < 8) {
            const float* p = Pr + (ksub*32 + tok)*25;
            const float* q = p + 16*25;
            #pragma unroll
            for (int l = 0; l < NL; ++l) { acc0[l] += p[l]; acc1[l] += q[l]; }
        }
        __syncthreads();
        if (ksub < 8) {
            float* p = Pr + (ksub*32 + tok)*25;
            float* q = p + 16*25;
            #pragma unroll
            for (int l = 0; l < NL; ++l) { p[l] = acc0[l]; q[l] = acc1[l]; }
        }
        __syncthreads();

        const int* tm = tlm + b*NS + tile;
        float* Eb = E + (size_t)(b*NS + tile)*NL;
        #pragma unroll
        for (int i = 0; i < 3; ++i) {
            int o = tid + (i << 8);                 // 0..767 (32 tok x 24 lab)
            int t = o / NL, l = o % NL;
            if (tm[t]) {
                float s = 0.f;
                #pragma unroll
                for (int ks = 0; ks < 8; ++ks)      // fixed ascending order
                    s += Pr[(ks*32 + t)*25 + l];
                float x = s + bias[l];
                Eb[t*NL + l] = 1.0f/(1.0f + expf(-x));
            }
        }
        __syncthreads();                            // all E stores issued by the block
        if (tid == 0)
            __hip_atomic_store(flags + bid, 1, __ATOMIC_RELEASE, __HIP_MEMORY_SCOPE_AGENT);
        return;
    }

    // ================= Viterbi consumer (R4 vit; em from global per tile) =========
    const int b  = blockIdx.x;
    const int bS = b*NS;

    float* scl = (float*)smem;                       // [NS][SCLS] = 28,672 B
    float* Tt  = (float*)(smem + 28672);             // [NL*NL]    =  2,304 B
    float* fin = (float*)(smem + 30976);             // [32]       =    128 B
    int*   chosen = (int*)(smem + 31104);            // [12]       =     48 B
    int*   misc   = (int*)(smem + 31152);            // [0]=n [1]=ltag
    unsigned char* tr_s = smem + 31160;              // [NL][NS]   =  6,144 B

    for (int i = tid; i < NL*NL; i += 256) {
        int cc = i / NL, p = i % NL;
        Tt[i] = trans[p*NL + cc];
    }
    if (tid < 64) {   // n = lengths[b]-2 (contiguous prefix mask)
        int a = tlm[bS+tid] + tlm[bS+tid+64] + tlm[bS+tid+128] + tlm[bS+tid+192];
        #pragma unroll
        for (int off = 32; off > 0; off >>= 1) a += __shfl_down(a, off, 64);
        if (tid == 0) misc[0] = a;
    }
    __syncthreads();
    const int n = misc[0];   // n >= 1 always

    // ---- forward: all 64 lanes of wave 0; lanes c and c+32 both own tag c ----
    if (tid < 64) {
        const int lane = tid;
        const int h    = lane >> 5;          // half: prev-tags [12h, 12h+12)
        const int c    = lane & 31;          // tag; c>=24 lanes garbage (never sourced)
        const int cidx = (c < 24) ? c : 23;  // clamped index for global reads
        const int coff = (c < 24) ? c : 24;  // scl column (24 = pad)
        const int p0   = h * 12;

        float Tc[12];
        #pragma unroll
        for (int j = 0; j < 12; ++j) Tc[j] = trans[(p0 + j)*NL + cidx];

        int idxv[12];
        #pragma unroll
        for (int j = 0; j < 12; ++j) idxv[j] = (p0 + j) << 2;

        auto bp = [](int idx4, float v) {   // pull lane (idx4/4)'s v — bit-exact
            return __int_as_float(__builtin_amdgcn_ds_bpermute(idx4, __float_as_int(v)));
        };

        const float* Eg = E + (size_t)bS*NL + cidx;  // row stride NL
        int* fl = flags + b*8;
        float sv = 0.f;

        auto step = [&](int t, float em) {
            float cand[12];
            #pragma unroll
            for (int j = 0; j < 12; ++j)     // 12 indep bpermutes
                cand[j] = bp(idxv[j], sv) + Tc[j];
            float a0 = fmaxf(fmaxf(cand[0], cand[1]),  cand[2]);
            float a1 = fmaxf(fmaxf(cand[3], cand[4]),  cand[5]);
            float a2 = fmaxf(fmaxf(cand[6], cand[7]),  cand[8]);
            float a3 = fmaxf(fmaxf(cand[9], cand[10]), cand[11]);
            float pm = fmaxf(fmaxf(a0, a1), fmaxf(a2, a3));   // partial over 12 prevs
#if __has_builtin(__builtin_amdgcn_permlane32_swap)
            auto r = __builtin_amdgcn_permlane32_swap(
                         __float_as_int(pm), __float_as_int(pm), false, false);
            float best = fmaxf(__int_as_float(r[0]), __int_as_float(r[1]));
#else
            float best = fmaxf(pm, bp((lane ^ 32) << 2, pm));
#endif
            sv = best + em;
            scl[t*SCLS + coff] = sv;         // off critical path (backtrack input)
        };

        const int jmax = (n - 1) >> 5;       // tiles 0..jmax cover rows 0..n-1
        for (int jt = 0; jt <= jmax; ++jt) {
            // wait for this tile's producer (wave-uniform spin, same address)
            while (__hip_atomic_load(fl + jt, __ATOMIC_RELAXED, __HIP_MEMORY_SCOPE_AGENT) == 0)
                __builtin_amdgcn_s_sleep(2);
            __threadfence();                 // acquire: invalidate caches before E reads

            float em[32];
            #pragma unroll
            for (int i = 0; i < 32; ++i)     // static reg indexing (no scratch)
                em[i] = Eg[(size_t)((jt << 5) + i)*NL];

            if (jt == 0) {                   // t=0 init uses row 0
                sv = st[cidx] + em[0];
                scl[coff] = sv;
            }
            #pragma unroll
            for (int i = 0; i < 32; ++i) {
                const int t = (jt << 5) + i;
                if (t >= 1 && t < n) step(t, em[i]);   // wave-uniform guard
            }
        }
        fin[c] = sv + en[cidx];              // c>=24 -> pad slots of fin[32]
    }
    __syncthreads();

    if (tid == 0) {   // argmax(final), first-max tie rule like jnp.argmax
        float bv = fin[0]; int bt = 0;
        #pragma unroll
        for (int cc = 1; cc < 24; ++cc) { if (fin[cc] > bv) { bv = fin[cc]; bt = cc; } }
        misc[1] = bt;
    }
    __syncthreads();
    const int ltag = misc[1];

    // ---- backtrack: 10 windows x 24 hypotheses, recompute backpointers ----
    const int K = (n > 1) ? (n - 1 + 9) / 10 : 1;
    if (n > 1 && tid < 240) {
        const int w = tid / 24 + 1, h = tid % 24;
        int tlo = (w-1)*K; if (tlo > n-1) tlo = n-1;
        int thi = w*K;     if (thi > n-1) thi = n-1;
        int cur = h;
        for (int t = thi; t > tlo; --t) {
            const float4* sp = (const float4*)(scl + (t-1)*SCLS);
            const float4* up = (const float4*)(Tt  + cur*NL);
            float cand[24];
            #pragma unroll
            for (int i = 0; i < 6; ++i) {
                float4 s = sp[i], u = up[i];
                cand[4*i+0] = s.x + u.x;     // bitwise-identical to forward cand
                cand[4*i+1] = s.y + u.y;
                cand[4*i+2] = s.z + u.z;
                cand[4*i+3] = s.w + u.w;
            }
            float best = cand[0]; int arg = 0;
            #pragma unroll
            for (int p = 1; p < 24; ++p) { if (cand[p] > best) { best = cand[p]; arg = p; } }
            tr_s[h*NS + (t-1)] = (unsigned char)arg;
            cur = arg;
        }
    }
    __syncthreads();

    if (tid == 0) {   // stitch windows
        int cur = ltag;
        for (int w = 10; w >= 1; --w) {
            chosen[w] = cur;
            int tlo = (w-1)*K; if (tlo > n-1) tlo = n-1;
            int thi = w*K;     if (thi > n-1) thi = n-1;
            if (thi > tlo) cur = tr_s[cur*NS + tlo];
        }
    }
    __syncthreads();

    {   // emit path: t >= n-1 -> last_tag (identity backpointers on padding)
        const int t = tid;
        int tag;
        if (t >= n-1) tag = ltag;
        else { int w = t / K + 1; tag = tr_s[chosen[w]*NS + t]; }
        out[bS + t] = tag;
    }
}

extern "C" void kernel_launch(void* const* d_in, const int* in_sizes, int n_in,
                              void* d_out, int out_size, void* d_ws, size_t ws_size,
                              hipStream_t stream) {
    const float* tf    = (const float*)d_in[0];
    const int*   tlm   = (const int*)  d_in[2];   // true_label_mask
    const float* W     = (const float*)d_in[3];
    const float* bias  = (const float*)d_in[4];
    const float* trans = (const float*)d_in[5];
    const float* st    = (const float*)d_in[6];
    const float* en    = (const float*)d_in[7];
    float* E     = (float*)d_ws;                           // [128,256,24] fp32
    int*   flags = (int*)((char*)d_ws + E_BYTES);          // [128*8] per-tile flags

    hipMemsetAsync(flags, 0, NB*8*sizeof(int), stream);    // ws re-poisoned per iter
    ner_fused<<<dim3(NB + NB*8), dim3(256), 0, stream>>>(
        tf, tlm, W, bias, trans, st, en, E, flags, (int*)d_out);
}